// Round 3
// baseline (139.703 us; speedup 1.0000x reference)
//
#include <hip/hip_runtime.h>
#include <stdint.h>
#include <math.h>

#define H 8
#define DH 64
#define T 2048
#define D 512
#define B 2
#define BH 16
#define MAXREL 32
#define NREL (2*MAXREL+1)
#define C1 0.18033688f           /* 0.125 * log2(e) */
#define NW (D*D)

typedef _Float16 half_t;
typedef half_t half8 __attribute__((ext_vector_type(8)));
typedef half_t half4 __attribute__((ext_vector_type(4)));
typedef float f32x4 __attribute__((ext_vector_type(4)));
typedef int int4v __attribute__((ext_vector_type(4)));

typedef __attribute__((address_space(3))) unsigned int lds_uint;
typedef const __attribute__((address_space(1))) unsigned int glb_uint;

__device__ __forceinline__ void gl_lds16(const void* g, void* l) {
    __builtin_amdgcn_global_load_lds((glb_uint*)g, (lds_uint*)l, 16, 0, 0);
}
__device__ __forceinline__ f32x4 zero4() { f32x4 z = {0.f,0.f,0.f,0.f}; return z; }
__device__ __forceinline__ int pkrtz(float a, float b) {
    return __builtin_bit_cast(int, __builtin_amdgcn_cvt_pkrtz(a, b));
}

// ---------------------------------------------------------------------------
// prep: blocks [0,1024): X fp32 -> fp16.  blocks [1024,1280): W^T fp16.
// Wts holds Wq^T, Wk^T, Wv^T, Wo^T (each [n][k] fp16).
// ---------------------------------------------------------------------------
__global__ __launch_bounds__(256) void prep(
    const float* __restrict__ X,
    const float* __restrict__ Wq, const float* __restrict__ Wk,
    const float* __restrict__ Wv, const float* __restrict__ Wo,
    half_t* __restrict__ Xh, half_t* __restrict__ Wts)
{
    __shared__ half_t Ld[64 * 72];
    const int bid = blockIdx.x;
    const int tid = threadIdx.x;
    if (bid < 1024) {
        const int i = (bid * 256 + tid) * 8;
        const float4 a = *(const float4*)(X + i);
        const float4 b = *(const float4*)(X + i + 4);
        half8 o;
        o[0]=(half_t)a.x; o[1]=(half_t)a.y; o[2]=(half_t)a.z; o[3]=(half_t)a.w;
        o[4]=(half_t)b.x; o[5]=(half_t)b.y; o[6]=(half_t)b.z; o[7]=(half_t)b.w;
        *(half8*)(Xh + i) = o;
    } else {
        const int id = bid - 1024;
        const int z = id >> 6;
        const int tile = id & 63;
        const float* __restrict__ W = (z==0)?Wq:(z==1)?Wk:(z==2)?Wv:Wo;
        half_t* __restrict__ out = Wts + (size_t)z * NW;
        const int k0 = (tile >> 3) * 64;
        const int n0 = (tile & 7) * 64;
        const int r = tid >> 2, c16 = (tid & 3) * 16;
        const float* src = W + (size_t)(k0 + r) * D + n0 + c16;
        #pragma unroll
        for (int j = 0; j < 16; ++j) Ld[r * 72 + c16 + j] = (half_t)src[j];
        __syncthreads();
        half_t tmp[16];
        #pragma unroll
        for (int j = 0; j < 16; ++j) tmp[j] = Ld[(c16 + j) * 72 + r];
        half8* dst = (half8*)(out + (size_t)(n0 + r) * D + k0 + c16);
        dst[0] = *(half8*)&tmp[0];
        dst[1] = *(half8*)&tmp[8];
    }
}

// ---------------------------------------------------------------------------
// QKV GEMM: C = Xh(4096x512) @ W + b.  64m x 128n, BK=64, dbuf staging,
// XOR(r&7)-swizzled 128B LDS rows.  z=0 Q [bh][t][d]; z=1 K [bh][t][d];
// z=2 V written TRANSPOSED [bh][d][t].  grid (64,4,3).
// ---------------------------------------------------------------------------
__global__ __launch_bounds__(256) void gemm_qkv(
    const half_t* __restrict__ Xh, const half_t* __restrict__ Wts,
    const float* __restrict__ bq, const float* __restrict__ bk,
    const float* __restrict__ bv,
    half_t* __restrict__ Qh, half_t* __restrict__ Kh, half_t* __restrict__ Vth)
{
    __shared__ half_t As[2][64 * 64];
    __shared__ half_t Bs[2][128 * 64];
    const int tid = threadIdx.x, w = tid >> 6, lane = tid & 63;
    const int l15 = lane & 15, quad = lane >> 4;
    const int m0 = blockIdx.x * 64, n0 = blockIdx.y * 128, z = blockIdx.z;
    const half_t* __restrict__ Wt = Wts + (size_t)z * NW;
    const float* __restrict__ bias = (z==0)?bq:(z==1)?bk:bv;

    auto stage = [&](int buf, int k0) {
        #pragma unroll
        for (int s = 0; s < 2; ++s) {
            const int cid = (w * 2 + s) * 64 + lane;
            const int r = cid >> 3, c = (cid & 7) ^ (r & 7);
            gl_lds16(Xh + (size_t)(m0 + r) * D + k0 + c * 8,
                     &As[buf][(w * 2 + s) * 512]);
        }
        #pragma unroll
        for (int s = 0; s < 4; ++s) {
            const int cid = (w * 4 + s) * 64 + lane;
            const int r = cid >> 3, c = (cid & 7) ^ (r & 7);
            gl_lds16(Wt + (size_t)(n0 + r) * D + k0 + c * 8,
                     &Bs[buf][(w * 4 + s) * 512]);
        }
    };

    f32x4 acc[4][2];
    #pragma unroll
    for (int ms = 0; ms < 4; ++ms) { acc[ms][0] = zero4(); acc[ms][1] = zero4(); }

    stage(0, 0);
    __syncthreads();
    for (int it = 0; it < 8; ++it) {
        const int cur = it & 1;
        if (it < 7) stage(cur ^ 1, (it + 1) * 64);
        const int swiz = l15 & 7;
        #pragma unroll
        for (int ks = 0; ks < 2; ++ks) {
            const int c = (ks * 4 + quad) ^ swiz;
            half8 bf[2];
            #pragma unroll
            for (int nt = 0; nt < 2; ++nt)
                bf[nt] = *(const half8*)&Bs[cur][(w * 32 + nt * 16 + l15) * 64 + c * 8];
            #pragma unroll
            for (int ms = 0; ms < 4; ++ms) {
                const half8 af = *(const half8*)&As[cur][(ms * 16 + l15) * 64 + c * 8];
                acc[ms][0] = __builtin_amdgcn_mfma_f32_16x16x32_f16(af, bf[0], acc[ms][0], 0, 0, 0);
                acc[ms][1] = __builtin_amdgcn_mfma_f32_16x16x32_f16(af, bf[1], acc[ms][1], 0, 0, 0);
            }
        }
        __syncthreads();
    }

    float bvv[2];
    #pragma unroll
    for (int nt = 0; nt < 2; ++nt) bvv[nt] = bias[n0 + w * 32 + nt * 16 + l15];

    if (z == 2) {
        // V transposed: Vth[((bb*H+h)*DH + d)*T + t], 4 t-contiguous per store
        #pragma unroll
        for (int ms = 0; ms < 4; ++ms) {
            const int mbase = m0 + ms * 16 + quad * 4;
            const int bb = mbase >> 11, t0 = mbase & 2047;
            #pragma unroll
            for (int nt = 0; nt < 2; ++nt) {
                const int n = n0 + w * 32 + nt * 16 + l15;
                const int hh = n >> 6, d = n & 63;
                half4 pk;
                #pragma unroll
                for (int r = 0; r < 4; ++r) pk[r] = (half_t)(acc[ms][nt][r] + bvv[nt]);
                *(half4*)(Vth + (((size_t)bb * H + hh) * DH + d) * T + t0) = pk;
            }
        }
    } else {
        half_t* __restrict__ dst = (z == 0) ? Qh : Kh;
        #pragma unroll
        for (int ms = 0; ms < 4; ++ms)
            #pragma unroll
            for (int nt = 0; nt < 2; ++nt)
                #pragma unroll
                for (int r = 0; r < 4; ++r) {
                    const int mrow = m0 + ms * 16 + quad * 4 + r;
                    const int n = n0 + w * 32 + nt * 16 + l15;
                    const int bb = mrow >> 11, t = mrow & 2047, hh = n >> 6, d = n & 63;
                    dst[(((size_t)bb * H + hh) * T + t) * DH + d] = (half_t)(acc[ms][nt][r] + bvv[nt]);
                }
    }
}

// ---------------------------------------------------------------------------
// Flash attention, S^T orientation.  Block = 64 q (4 waves x 16 q), 1-D grid
// 1024 blocks with XCD-bijective swizzle so each XCD owns 4 whole heads
// (K/V panels stay L2-resident).  Per 64-key tile: S^T = K.Q^T (8 mfma),
// exp2 softmax, quad-shuffle transpose of P (no LDS round-trip), O^T +=
// V^T.P^T (8 mfma).  Writes unnormalized O/64 fp16 + rowsum l/64 fp16.
// ---------------------------------------------------------------------------
__global__ __launch_bounds__(256) void attn_fwd(
    const half_t* __restrict__ Qh, const half_t* __restrict__ Kh,
    const half_t* __restrict__ Vth, const float* __restrict__ relb,
    half_t* __restrict__ Onum, half_t* __restrict__ lsum)
{
    __shared__ half_t Kt[2][4096];   // [key][d], XOR(r&7) chunk swizzle
    __shared__ half_t Vt[2][4096];   // [d][key], same swizzle
    __shared__ float rb2[NREL];

    const int tid = threadIdx.x, w = tid >> 6, lane = tid & 63;
    const int l15 = lane & 15, quad = lane >> 4;

    // XCD-bijective swizzle: 1024 blocks, 8 XCDs -> each XCD gets 128
    // consecutive logical ids = 4 whole heads of one split (2 MB K+V in L2).
    const int bid0 = blockIdx.x;
    const int nid = (bid0 & 7) * 128 + (bid0 >> 3);
    const int qb = nid & 31;
    const int bh = (nid >> 5) & 15;
    const int split = nid >> 9;

    const int q0 = qb * 64;
    const int qw = q0 + w * 16;              // this wave's 16 q-rows
    const int kb0 = split * 1024;
    const int h = bh & 7;

    if (tid < NREL) rb2[tid] = relb[h * NREL + tid] * 1.44269504f;

    // Q as B-operand: n=q=l15(+qw), k = ks*32 + quad*8 + j
    half8 qf[2];
    const half_t* Qbase = Qh + ((size_t)bh * T + qw) * DH;
    #pragma unroll
    for (int ks = 0; ks < 2; ++ks)
        qf[ks] = *(const half8*)(Qbase + l15 * DH + ks * 32 + quad * 8);

    f32x4 of[4];
    #pragma unroll
    for (int nt = 0; nt < 4; ++nt) of[nt] = zero4();
    float lp = 0.f;

    auto stage = [&](int buf, int kb) {
        #pragma unroll
        for (int s = 0; s < 2; ++s) {
            const int cid = (w * 2 + s) * 64 + lane;
            const int r = cid >> 3, cg = (cid & 7) ^ (r & 7);
            gl_lds16(Kh + ((size_t)bh * T + kb + r) * DH + cg * 8,
                     &Kt[buf][(w * 2 + s) * 512]);
            gl_lds16(Vth + ((size_t)bh * DH + r) * T + kb + cg * 8,
                     &Vt[buf][(w * 2 + s) * 512]);
        }
    };

    stage(0, kb0);
    __syncthreads();

    const int qg = qw + l15;
    const int swiz = l15 & 7;

    for (int it = 0; it < 16; ++it) {
        const int cur = it & 1;
        if (it + 1 < 16) stage(cur ^ 1, kb0 + (it + 1) * 64);
        const int kb = kb0 + it * 64;

        // S^T = K . Q^T : A = K-frag (m=key), B = Q-frag (n=q)
        f32x4 st[4];
        #pragma unroll
        for (int nt = 0; nt < 4; ++nt) st[nt] = zero4();
        __builtin_amdgcn_s_setprio(1);
        #pragma unroll
        for (int ks = 0; ks < 2; ++ks) {
            const int c = (ks * 4 + quad) ^ swiz;
            #pragma unroll
            for (int nt = 0; nt < 4; ++nt) {
                const half8 kf = *(const half8*)&Kt[cur][(nt * 16 + l15) * 64 + c * 8];
                st[nt] = __builtin_amdgcn_mfma_f32_16x16x32_f16(kf, qf[ks], st[nt], 0, 0, 0);
            }
        }
        __builtin_amdgcn_s_setprio(0);

        // softmax (exp2, no max — S bounded) ; pack P^T to fp16 dwords
        int pd[4][2];
        const bool uni_hi = (qw - (kb + 63)) >= MAXREL;
        const bool uni_lo = ((qw + 15) - kb) <= -MAXREL;
        if (uni_hi || uni_lo) {
            const float bu = uni_hi ? rb2[NREL - 1] : rb2[0];
            #pragma unroll
            for (int nt = 0; nt < 4; ++nt) {
                float p[4];
                #pragma unroll
                for (int r = 0; r < 4; ++r) p[r] = exp2f(fmaf(st[nt][r], C1, bu));
                lp += (p[0] + p[1]) + (p[2] + p[3]);
                pd[nt][0] = pkrtz(p[0], p[1]);
                pd[nt][1] = pkrtz(p[2], p[3]);
            }
        } else {
            #pragma unroll
            for (int nt = 0; nt < 4; ++nt) {
                float p[4];
                #pragma unroll
                for (int r = 0; r < 4; ++r) {
                    const int key = kb + nt * 16 + quad * 4 + r;
                    int rel = qg - key;
                    rel = rel < -MAXREL ? -MAXREL : (rel > MAXREL ? MAXREL : rel);
                    p[r] = exp2f(fmaf(st[nt][r], C1, rb2[rel + MAXREL]));
                }
                lp += (p[0] + p[1]) + (p[2] + p[3]);
                pd[nt][0] = pkrtz(p[0], p[1]);
                pd[nt][1] = pkrtz(p[2], p[3]);
            }
        }

        // O^T += V^T . P^T : quad-shuffle C-layout -> B-layout, then mfma
        #pragma unroll
        for (int ks = 0; ks < 2; ++ks) {
            int4v bd;
            #pragma unroll
            for (int d = 0; d < 4; ++d) {
                const int src = ((quad & 1) * 2 + (d >> 1)) * 16 + l15;
                const int va = __shfl(pd[2 * ks][d & 1], src);
                const int vb = __shfl(pd[2 * ks + 1][d & 1], src);
                bd[d] = (quad >> 1) ? vb : va;
            }
            const half8 pf = __builtin_bit_cast(half8, bd);
            const int c = (ks * 4 + quad) ^ swiz;
            __builtin_amdgcn_s_setprio(1);
            #pragma unroll
            for (int nt = 0; nt < 4; ++nt) {
                const half8 vf = *(const half8*)&Vt[cur][(nt * 16 + l15) * 64 + c * 8];
                of[nt] = __builtin_amdgcn_mfma_f32_16x16x32_f16(vf, pf, of[nt], 0, 0, 0);
            }
            __builtin_amdgcn_s_setprio(0);
        }
        __syncthreads();
    }

    // epilogue: lane holds O^T for q = qw + l15, d = nt*16 + quad*4 + r
    const size_t qrow = (size_t)(split * BH + bh) * T + qw + l15;
    half_t* obase = Onum + qrow * DH;
    #pragma unroll
    for (int nt = 0; nt < 4; ++nt) {
        half4 pk;
        #pragma unroll
        for (int r = 0; r < 4; ++r) pk[r] = (half_t)(of[nt][r] * 0.015625f);
        *(half4*)(obase + nt * 16 + quad * 4) = pk;
    }
    lp += __shfl_xor(lp, 16);
    lp += __shfl_xor(lp, 32);
    if (quad == 0) lsum[qrow] = (half_t)(lp * 0.015625f);
}

// ---------------------------------------------------------------------------
// Output projection with FUSED split-combine:
// out = ((O0+O1)/(l0+l1)) @ Wo + bo, fp32 out.  32m x 128n, BK=64, dbuf.
// A-operand is reg-staged from Onum (2 splits) + normalized, then ds_write
// into the same XOR(r&7)-swizzled As layout (dest slot = tid, source chunk
// = (tid&7)^(row&7)) the MFMA loop reads.  B stays gl_lds16.  grid (128,4).
// Per k-iteration the 64-k slice spans exactly one head: bh row-uniform.
// ---------------------------------------------------------------------------
__global__ __launch_bounds__(256) void gemm_out(
    const half_t* __restrict__ Onum, const half_t* __restrict__ lsum,
    const half_t* __restrict__ Wot,
    const float* __restrict__ bo, float* __restrict__ out)
{
    __shared__ half_t As[2][32 * 64];
    __shared__ half_t Bs[2][128 * 64];
    const int tid = threadIdx.x, w = tid >> 6, lane = tid & 63;
    const int l15 = lane & 15, quad = lane >> 4;
    const int m0 = blockIdx.x * 32, n0 = blockIdx.y * 128;

    // fused-combine A staging: this thread owns LDS dest slot `tid`
    const int ar = tid >> 3;                 // tile row [0,32)
    const int ac = (tid & 7) ^ (ar & 7);     // source chunk (XOR swizzle)
    const int rr = m0 + ar;
    const int ab = rr >> 11, at = rr & 2047; // batch, t

    half8 x0, x1; half_t la, lb;
    auto loadA = [&](int k0) {               // issue-early (T14)
        const int bh = ab * H + (k0 >> 6);   // head uniform across the row
        const int d = ac * 8;
        x0 = *(const half8*)(Onum + ((size_t)bh * T + at) * DH + d);
        x1 = *(const half8*)(Onum + ((size_t)(BH + bh) * T + at) * DH + d);
        la = lsum[(size_t)bh * T + at];
        lb = lsum[(size_t)(BH + bh) * T + at];
    };
    auto writeA = [&](int buf) {             // write-late, after MFMA cluster
        const float inv = 1.0f / ((float)la + (float)lb);
        half8 o;
        #pragma unroll
        for (int j = 0; j < 8; ++j)
            o[j] = (half_t)(((float)x0[j] + (float)x1[j]) * inv);
        *(half8*)&As[buf][tid * 8] = o;
    };

    auto stageB = [&](int buf, int k0) {
        #pragma unroll
        for (int s = 0; s < 4; ++s) {
            const int cid = (w * 4 + s) * 64 + lane;
            const int r = cid >> 3, c = (cid & 7) ^ (r & 7);
            gl_lds16(Wot + (size_t)(n0 + r) * D + k0 + c * 8,
                     &Bs[buf][(w * 4 + s) * 512]);
        }
    };

    f32x4 acc[2][2];
    #pragma unroll
    for (int ms = 0; ms < 2; ++ms) { acc[ms][0] = zero4(); acc[ms][1] = zero4(); }

    loadA(0);
    stageB(0, 0);
    writeA(0);
    __syncthreads();
    for (int it = 0; it < 8; ++it) {
        const int cur = it & 1;
        if (it < 7) { loadA((it + 1) * 64); stageB(cur ^ 1, (it + 1) * 64); }
        const int swiz = l15 & 7;
        #pragma unroll
        for (int ks = 0; ks < 2; ++ks) {
            const int c = (ks * 4 + quad) ^ swiz;
            half8 bf[2];
            #pragma unroll
            for (int nt = 0; nt < 2; ++nt)
                bf[nt] = *(const half8*)&Bs[cur][(w * 32 + nt * 16 + l15) * 64 + c * 8];
            #pragma unroll
            for (int ms = 0; ms < 2; ++ms) {
                const half8 af = *(const half8*)&As[cur][(ms * 16 + l15) * 64 + c * 8];
                acc[ms][0] = __builtin_amdgcn_mfma_f32_16x16x32_f16(af, bf[0], acc[ms][0], 0, 0, 0);
                acc[ms][1] = __builtin_amdgcn_mfma_f32_16x16x32_f16(af, bf[1], acc[ms][1], 0, 0, 0);
            }
        }
        if (it < 7) writeA(cur ^ 1);
        __syncthreads();
    }

    float bvv[2];
    #pragma unroll
    for (int nt = 0; nt < 2; ++nt) bvv[nt] = bo[n0 + w * 32 + nt * 16 + l15];
    #pragma unroll
    for (int ms = 0; ms < 2; ++ms)
        #pragma unroll
        for (int nt = 0; nt < 2; ++nt)
            #pragma unroll
            for (int r = 0; r < 4; ++r) {
                const int mrow = m0 + ms * 16 + quad * 4 + r;
                const int n = n0 + w * 32 + nt * 16 + l15;
                out[(size_t)mrow * D + n] = acc[ms][nt][r] + bvv[nt];
            }
}

extern "C" void kernel_launch(void* const* d_in, const int* in_sizes, int n_in,
                              void* d_out, int out_size, void* d_ws, size_t ws_size,
                              hipStream_t stream)
{
    const float* hs   = (const float*)d_in[0];
    const float* Wq   = (const float*)d_in[1];
    const float* bq   = (const float*)d_in[2];
    const float* Wk   = (const float*)d_in[3];
    const float* bk   = (const float*)d_in[4];
    const float* Wv   = (const float*)d_in[5];
    const float* bv   = (const float*)d_in[6];
    const float* Wo   = (const float*)d_in[7];
    const float* bo   = (const float*)d_in[8];
    const float* relb = (const float*)d_in[9];

    // workspace (fp16 elements), total ~26 MB
    const size_t NX = (size_t)B * T * D;          // 2,097,152
    half_t* wsh = (half_t*)d_ws;
    half_t* Xh  = wsh;
    half_t* Wts = Xh + NX;            // Wq^T,Wk^T,Wv^T,Wo^T (4*NW)
    half_t* Qh  = Wts + 4 * (size_t)NW;
    half_t* Kh  = Qh + NX;
    half_t* Vth = Kh + NX;
    half_t* On  = Vth + NX;           // 2 splits
    half_t* Ls  = On + 2 * NX;        // 2*BH*T

    prep    <<<dim3(1280), 256, 0, stream>>>(hs, Wq, Wk, Wv, Wo, Xh, Wts);
    gemm_qkv<<<dim3(64, 4, 3), 256, 0, stream>>>(Xh, Wts, bq, bk, bv, Qh, Kh, Vth);
    attn_fwd<<<dim3(1024), 256, 0, stream>>>(Qh, Kh, Vth, relb, On, Ls);
    gemm_out<<<dim3(128, 4), 256, 0, stream>>>(On, Ls, Wts + 3 * (size_t)NW, bo, (float*)d_out);
}